// Round 1
// baseline (44068.430 us; speedup 1.0000x reference)
//
#include <hip/hip_runtime.h>
#include <stdint.h>

#define T_STEPS 784
#define H 256
#define NBATCH 512
#define S_PER_BLK 4
#define NBLK (NBATCH / S_PER_BLK)   // 128 blocks
#define NTHR 512                    // 8 waves: thread = (j = tid&255, g = tid>>8)

// Per-neuron mask parameters, replicating numpy linspace/ceil/round in float64.
// numpy: step = (stop-start)/(num-1); y = arange*step; y += start; y[-1] = stop.
__device__ __forceinline__ void mask_params(int j, int& c, int& on, int& ps) {
    const double stepc = (8.0 - 4.0) / 255.0;
    const double stepd = (0.9 - 0.1) / 255.0;
    const double stepp = 4.0 / 255.0;      // int(0.5*8) = 4 ; start = 0
    double cyc = (j == 255) ? 8.0 : __dadd_rn(__dmul_rn((double)j, stepc), 4.0);
    c = (int)ceil(cyc);
    double dc  = (j == 255) ? 0.9 : __dadd_rn(__dmul_rn((double)j, stepd), 0.1);
    on = (int)ceil(__dmul_rn(dc, (double)c));
    double psd = (j == 255) ? 4.0 : __dmul_rn((double)j, stepp);
    ps = (int)rint(psd);                   // round-half-even == np.round
}

// 256-long masked row dot: acc[s] = sum_k bit_s(k) * row[k], two samples.
// Masks come from LDS; readfirstlane forces SGPR so the bit-selects are SALU
// and the MAC is v_fmac_f32 vacc, s_f, v_w (1 VALU/MAC).
__device__ __forceinline__ void matvec(const float4* __restrict__ row,
                                       const unsigned long long (*um)[4],
                                       int sl0, int sl1, float& o0, float& o1)
{
    float acc0 = 0.0f, acc1 = 0.0f;
    for (int kb = 0; kb < 4; kb++) {
        unsigned long long v0 = um[sl0][kb];
        unsigned long long v1 = um[sl1][kb];
        unsigned int lo0 = __builtin_amdgcn_readfirstlane((unsigned int)v0);
        unsigned int hi0 = __builtin_amdgcn_readfirstlane((unsigned int)(v0 >> 32));
        unsigned int lo1 = __builtin_amdgcn_readfirstlane((unsigned int)v1);
        unsigned int hi1 = __builtin_amdgcn_readfirstlane((unsigned int)(v1 >> 32));
        unsigned long long m0 = ((unsigned long long)hi0 << 32) | lo0;
        unsigned long long m1 = ((unsigned long long)hi1 << 32) | lo1;
        const float4* rp = row + kb * 16;
        #pragma unroll
        for (int q = 0; q < 16; q++) {
            float4 w = rp[q];
            const int k = q * 4;
            float f;
            f = ((m0 >> (k + 0)) & 1ull) ? 1.0f : 0.0f; acc0 = fmaf(f, w.x, acc0);
            f = ((m1 >> (k + 0)) & 1ull) ? 1.0f : 0.0f; acc1 = fmaf(f, w.x, acc1);
            f = ((m0 >> (k + 1)) & 1ull) ? 1.0f : 0.0f; acc0 = fmaf(f, w.y, acc0);
            f = ((m1 >> (k + 1)) & 1ull) ? 1.0f : 0.0f; acc1 = fmaf(f, w.y, acc1);
            f = ((m0 >> (k + 2)) & 1ull) ? 1.0f : 0.0f; acc0 = fmaf(f, w.z, acc0);
            f = ((m1 >> (k + 2)) & 1ull) ? 1.0f : 0.0f; acc1 = fmaf(f, w.z, acc1);
            f = ((m0 >> (k + 3)) & 1ull) ? 1.0f : 0.0f; acc0 = fmaf(f, w.w, acc0);
            f = ((m1 >> (k + 3)) & 1ull) ? 1.0f : 0.0f; acc1 = fmaf(f, w.w, acc1);
        }
    }
    o0 = acc0; o1 = acc1;
}

// mem_update: new = mem*0.5*(1-spk) + h; mem = mask? new : mem; spk = mask & (mem>0.5)
__device__ __forceinline__ void upd(float& mem, float& sp, float h, int mbit) {
    float nm = fmaf(mem * 0.5f, (1.0f - sp), h);
    mem = mbit ? nm : mem;
    sp  = (mbit && (mem > 0.5f)) ? 1.0f : 0.0f;
}

__global__ __launch_bounds__(NTHR, 2)
void srnn_kernel(const float* __restrict__ x,
                 const float* __restrict__ w_i2h1, const float* __restrict__ b_i2h1,
                 const float* __restrict__ w_h2h1, const float* __restrict__ b_h2h1,
                 const float* __restrict__ w_i2h2, const float* __restrict__ b_i2h2,
                 const float* __restrict__ w_h2h2, const float* __restrict__ b_h2h2,
                 const float* __restrict__ w_i2h3, const float* __restrict__ b_i2h3,
                 const float* __restrict__ w_h2o3, const float* __restrict__ b_h2o3,
                 float* __restrict__ out)
{
    const int tid  = threadIdx.x;
    const int j    = tid & 255;
    const int g    = tid >> 8;            // sample-pair group 0/1 (no k-split: both read same rows, L1 shares)
    const int kblk = (tid >> 6) & 3;      // which 64-bit block this wave's j-range covers
    const int lane = tid & 63;
    const int wave = tid >> 6;
    const int s_base = blockIdx.x * S_PER_BLK;
    const int sl0 = 2 * g, sl1 = 2 * g + 1;

    __shared__ float xls[S_PER_BLK][T_STEPS];              // 12.25 KB input slice
    __shared__ unsigned long long umask1[S_PER_BLK][4];    // layer-1 spike bitmasks
    __shared__ unsigned long long umask2[S_PER_BLK][4];    // layer-2 spike bitmasks
    __shared__ float wred[8][2][10];                       // final output reduction

    // Stage x rows for this block's 4 samples into LDS.
    for (int i = tid; i < S_PER_BLK * T_STEPS; i += NTHR) {
        int s = i / T_STEPS, t = i - s * T_STEPS;
        xls[s][t] = x[(size_t)(s_base + s) * T_STEPS + t];
    }
    if (tid < S_PER_BLK * 4) {
        ((unsigned long long*)umask1)[tid] = 0ull;
        ((unsigned long long*)umask2)[tid] = 0ull;
    }

    // Static mask schedule for neuron j (same for all 3 layers: identical make_mask args).
    int mc, mon, mps;
    mask_params(j, mc, mon, mps);
    int ph = (mc - (mps % mc)) % mc;      // (t - ps) mod c at t = 0

    // Per-thread constants.
    const float bs1 = b_i2h1[j] + b_h2h1[j];
    const float bs2 = b_i2h2[j] + b_h2h2[j];
    const float bs3 = b_i2h3[j];
    const float wi1 = w_i2h1[j];
    float wo[10];
    #pragma unroll
    for (int i = 0; i < 10; i++) wo[i] = w_h2o3[i * H + j];

    const float4* rowW1  = (const float4*)(w_h2h1 + (size_t)j * H);
    const float4* rowW2a = (const float4*)(w_i2h2 + (size_t)j * H);
    const float4* rowW2b = (const float4*)(w_h2h2 + (size_t)j * H);
    const float4* rowW3  = (const float4*)(w_i2h3 + (size_t)j * H);

    // Private state: this thread's neuron j for its two samples.
    float mem1[2] = {0.f, 0.f}, mem2[2] = {0.f, 0.f}, mem3[2] = {0.f, 0.f};
    float sp1 [2] = {0.f, 0.f}, sp2 [2] = {0.f, 0.f}, sp3 [2] = {0.f, 0.f};
    float oacc[2][10];
    #pragma unroll
    for (int i = 0; i < 10; i++) { oacc[0][i] = 0.f; oacc[1][i] = 0.f; }

    __syncthreads();

    for (int t = 0; t < T_STEPS; t++) {
        const int mbit = (ph < mon) ? 1 : 0;

        // ---- layer 1: h1 = x*wi + spk1_old@W1.T + biases
        float a0, a1;
        matvec(rowW1, umask1, sl0, sl1, a0, a1);
        float h1_0 = a0 + fmaf(xls[sl0][t], wi1, bs1);
        float h1_1 = a1 + fmaf(xls[sl1][t], wi1, bs1);
        __syncthreads();                                   // (1) done reading umask1 old
        upd(mem1[0], sp1[0], h1_0, mbit);
        upd(mem1[1], sp1[1], h1_1, mbit);
        {
            unsigned long long bl0 = __ballot(sp1[0] != 0.0f);
            unsigned long long bl1 = __ballot(sp1[1] != 0.0f);
            if (lane == 0) { umask1[sl0][kblk] = bl0; umask1[sl1][kblk] = bl1; }
        }
        __syncthreads();                                   // (2) umask1 new visible

        // ---- layer 2: h2 = spk1_new@W2a.T + spk2_old@W2b.T + biases
        float c0, c1, d0, d1;
        matvec(rowW2a, umask1, sl0, sl1, c0, c1);
        matvec(rowW2b, umask2, sl0, sl1, d0, d1);
        float h2_0 = c0 + d0 + bs2;
        float h2_1 = c1 + d1 + bs2;
        __syncthreads();                                   // (3) done reading umask2 old
        upd(mem2[0], sp2[0], h2_0, mbit);
        upd(mem2[1], sp2[1], h2_1, mbit);
        {
            unsigned long long bl0 = __ballot(sp2[0] != 0.0f);
            unsigned long long bl1 = __ballot(sp2[1] != 0.0f);
            if (lane == 0) { umask2[sl0][kblk] = bl0; umask2[sl1][kblk] = bl1; }
        }
        __syncthreads();                                   // (4) umask2 new visible

        // ---- layer 3: h3 = spk2_new@W3.T + b  (spk3/mem3 fully private)
        float e0, e1;
        matvec(rowW3, umask2, sl0, sl1, e0, e1);
        upd(mem3[0], sp3[0], e0 + bs3, mbit);
        upd(mem3[1], sp3[1], e1 + bs3, mbit);

        // ---- output accumulation: out += spk3 * w_o column j
        #pragma unroll
        for (int i = 0; i < 10; i++) {
            oacc[0][i] = fmaf(sp3[0], wo[i], oacc[0][i]);
            oacc[1][i] = fmaf(sp3[1], wo[i], oacc[1][i]);
        }

        ph++; if (ph == mc) ph = 0;
    }

    // ---- final reduction over j (and g-waves) for out[s][i]
    #pragma unroll
    for (int sl = 0; sl < 2; sl++) {
        #pragma unroll
        for (int i = 0; i < 10; i++) {
            float v = oacc[sl][i];
            for (int off = 32; off; off >>= 1) v += __shfl_down(v, off, 64);
            if (lane == 0) wred[wave][sl][i] = v;
        }
    }
    __syncthreads();
    if (tid < S_PER_BLK * 10) {
        int s = tid / 10, i = tid % 10;
        int gq = s >> 1, sl = s & 1;
        float sum = 0.f;
        for (int w = 0; w < 4; w++) sum += wred[gq * 4 + w][sl][i];
        out[(size_t)(s_base + s) * 10 + i] = sum / 784.0f + b_h2o3[i];
    }
}

extern "C" void kernel_launch(void* const* d_in, const int* in_sizes, int n_in,
                              void* d_out, int out_size, void* d_ws, size_t ws_size,
                              hipStream_t stream) {
    (void)in_sizes; (void)n_in; (void)d_ws; (void)ws_size; (void)out_size;
    const float* x      = (const float*)d_in[0];
    const float* w_i2h1 = (const float*)d_in[1];
    const float* b_i2h1 = (const float*)d_in[2];
    const float* w_h2h1 = (const float*)d_in[3];
    const float* b_h2h1 = (const float*)d_in[4];
    const float* w_i2h2 = (const float*)d_in[5];
    const float* b_i2h2 = (const float*)d_in[6];
    const float* w_h2h2 = (const float*)d_in[7];
    const float* b_h2h2 = (const float*)d_in[8];
    const float* w_i2h3 = (const float*)d_in[9];
    const float* b_i2h3 = (const float*)d_in[10];
    const float* w_h2o3 = (const float*)d_in[11];
    const float* b_h2o3 = (const float*)d_in[12];
    srnn_kernel<<<NBLK, NTHR, 0, stream>>>(x,
        w_i2h1, b_i2h1, w_h2h1, b_h2h1,
        w_i2h2, b_i2h2, w_h2h2, b_h2h2,
        w_i2h3, b_i2h3, w_h2o3, b_h2o3,
        (float*)d_out);
}

// Round 2
// 9199.062 us; speedup vs baseline: 4.7905x; 4.7905x over previous
//
#include <hip/hip_runtime.h>
#include <stdint.h>

#define T_STEPS 784
#define H 256
#define NBATCH 512
#define S_PER_BLK 4
#define NBLK (NBATCH / S_PER_BLK)   // 128 blocks
#define NTHR 512                    // 8 waves = 4 j-groups x 2 sample-groups

typedef unsigned long long u64;

// Per-neuron mask parameters, replicating numpy linspace/ceil/round in float64.
__device__ __forceinline__ void mask_params(int j, int& c, int& on, int& ps) {
    const double stepc = (8.0 - 4.0) / 255.0;
    const double stepd = (0.9 - 0.1) / 255.0;
    const double stepp = 4.0 / 255.0;
    double cyc = (j == 255) ? 8.0 : __dadd_rn(__dmul_rn((double)j, stepc), 4.0);
    c = (int)ceil(cyc);
    double dc  = (j == 255) ? 0.9 : __dadd_rn(__dmul_rn((double)j, stepd), 0.1);
    on = (int)ceil(__dmul_rn(dc, (double)c));
    double psd = (j == 255) ? 4.0 : __dmul_rn((double)j, stepp);
    ps = (int)rint(psd);
}

__device__ __forceinline__ u64 rfl64(u64 v) {
    unsigned int lo = __builtin_amdgcn_readfirstlane((unsigned int)v);
    unsigned int hi = __builtin_amdgcn_readfirstlane((unsigned int)(v >> 32));
    return ((u64)hi << 32) | lo;
}

// Sparse masked column-sum over transposed weights.
// mat: block-uniform base of WT[k][j] (k-major). joff: this thread's j (lane-contiguous).
// acc_s = sum_{k: bit_s(k)} WT[k][joff]. Spikes are exactly 1.0 -> pure adds.
// 3-way mask split (both / only-s0 / only-s1): no per-k selects, minimal adds.
// 2-deep pipeline: 2 loads in flight, 2 accumulator chains.
__device__ __forceinline__ void matvec_sp(const float* __restrict__ mat, int joff,
                                          const u64* __restrict__ ma,
                                          const u64* __restrict__ mb,
                                          float& o0, float& o1)
{
    float a0 = 0.f, b0 = 0.f, a1 = 0.f, b1 = 0.f;
    #pragma unroll
    for (int wd = 0; wd < 4; wd++) {
        u64 m0 = rfl64(ma[wd]);
        u64 m1 = rfl64(mb[wd]);
        u64 bo = m0 & m1;
        u64 e0 = m0 & ~m1;
        u64 e1 = m1 & ~m0;
        const float* base = mat + (size_t)(wd * 64) * H + joff;
        while (bo) {
            int k1 = __builtin_ctzll(bo); bo &= bo - 1;
            float w1 = base[(size_t)k1 * H];
            if (bo) {
                int k2 = __builtin_ctzll(bo); bo &= bo - 1;
                float w2 = base[(size_t)k2 * H];
                a0 += w1; b0 += w2; a1 += w1; b1 += w2;
            } else { a0 += w1; a1 += w1; }
        }
        while (e0) {
            int k1 = __builtin_ctzll(e0); e0 &= e0 - 1;
            float w1 = base[(size_t)k1 * H];
            if (e0) {
                int k2 = __builtin_ctzll(e0); e0 &= e0 - 1;
                float w2 = base[(size_t)k2 * H];
                a0 += w1; b0 += w2;
            } else { a0 += w1; }
        }
        while (e1) {
            int k1 = __builtin_ctzll(e1); e1 &= e1 - 1;
            float w1 = base[(size_t)k1 * H];
            if (e1) {
                int k2 = __builtin_ctzll(e1); e1 &= e1 - 1;
                float w2 = base[(size_t)k2 * H];
                a1 += w1; b1 += w2;
            } else { a1 += w1; }
        }
    }
    o0 = a0 + b0; o1 = a1 + b1;
}

__device__ __forceinline__ void upd(float& mem, float& sp, float h, int mbit) {
    float nm = fmaf(mem * 0.5f, (1.0f - sp), h);
    mem = mbit ? nm : mem;
    sp  = (mbit && (mem > 0.5f)) ? 1.0f : 0.0f;
}

// Tiled transpose of the 4 weight matrices into ws: WT[k][j] = W[j][k].
__global__ __launch_bounds__(256)
void prep_transpose(const float* __restrict__ w1, const float* __restrict__ w2a,
                    const float* __restrict__ w2b, const float* __restrict__ w3,
                    float* __restrict__ ws)
{
    __shared__ float tile[64][65];
    const int bid = blockIdx.x;                 // 64 blocks: m(4) x kt(4) x jt(4)
    const int m  = bid >> 4;
    const int kt = (bid >> 2) & 3;
    const int jt = bid & 3;
    const float* src = (m == 0) ? w1 : (m == 1) ? w2a : (m == 2) ? w2b : w3;
    float* dst = ws + (size_t)m * H * H;
    const int tid = threadIdx.x;
    const int c = tid & 63, r4 = tid >> 6;
    #pragma unroll
    for (int rr = 0; rr < 16; rr++) {
        int r = r4 * 16 + rr;
        tile[r][c] = src[(size_t)(jt * 64 + r) * H + kt * 64 + c];
    }
    __syncthreads();
    #pragma unroll
    for (int rr = 0; rr < 16; rr++) {
        int r = r4 * 16 + rr;
        dst[(size_t)(kt * 64 + r) * H + jt * 64 + c] = tile[c][r];
    }
}

__global__ __launch_bounds__(NTHR, 2)
void srnn_kernel(const float* __restrict__ x,
                 const float* __restrict__ w_i2h1, const float* __restrict__ b_i2h1,
                 const float* __restrict__ b_h2h1,
                 const float* __restrict__ b_i2h2, const float* __restrict__ b_h2h2,
                 const float* __restrict__ b_i2h3,
                 const float* __restrict__ w_h2o3, const float* __restrict__ b_h2o3,
                 const float* __restrict__ ws,     // WT1 | WT2a | WT2b | WT3
                 float* __restrict__ out)
{
    const int tid  = threadIdx.x;
    const int lane = tid & 63;
    const int wave = tid >> 6;
    const int jg   = wave & 3;                  // j-group: j in [64*jg, 64*jg+64)
    const int sg   = wave >> 2;                 // sample-group: samples {2sg, 2sg+1}
    const int j    = jg * 64 + lane;
    const int sl0  = 2 * sg, sl1 = 2 * sg + 1;
    const int s_base = blockIdx.x * S_PER_BLK;

    const float* wt1  = ws;
    const float* wt2a = ws + 1 * H * H;
    const float* wt2b = ws + 2 * H * H;
    const float* wt3  = ws + 3 * H * H;

    __shared__ float xls[S_PER_BLK][T_STEPS];
    __shared__ u64 umask1[S_PER_BLK][4];
    __shared__ u64 umask2[S_PER_BLK][4];
    __shared__ float wred[8][2][10];

    for (int i = tid; i < S_PER_BLK * T_STEPS; i += NTHR) {
        int s = i / T_STEPS, t = i - s * T_STEPS;
        xls[s][t] = x[(size_t)(s_base + s) * T_STEPS + t];
    }
    if (tid < S_PER_BLK * 4) {
        ((u64*)umask1)[tid] = 0ull;
        ((u64*)umask2)[tid] = 0ull;
    }

    int mc, mon, mps;
    mask_params(j, mc, mon, mps);
    int ph = (mc - (mps % mc)) % mc;

    const float bs1 = b_i2h1[j] + b_h2h1[j];
    const float bs2 = b_i2h2[j] + b_h2h2[j];
    const float bs3 = b_i2h3[j];
    const float wi1 = w_i2h1[j];
    float wo[10];
    #pragma unroll
    for (int i = 0; i < 10; i++) wo[i] = w_h2o3[i * H + j];

    float mem1[2] = {0.f, 0.f}, mem2[2] = {0.f, 0.f}, mem3[2] = {0.f, 0.f};
    float sp1 [2] = {0.f, 0.f}, sp2 [2] = {0.f, 0.f}, sp3 [2] = {0.f, 0.f};
    float oacc[2][10];
    #pragma unroll
    for (int i = 0; i < 10; i++) { oacc[0][i] = 0.f; oacc[1][i] = 0.f; }

    __syncthreads();

    for (int t = 0; t < T_STEPS; t++) {
        const int mbit = (ph < mon) ? 1 : 0;

        // ---- layer 1: h1 = x*wi + spk1_old@W1.T + biases
        float a0, a1;
        matvec_sp(wt1, j, umask1[sl0], umask1[sl1], a0, a1);
        float h1_0 = a0 + fmaf(xls[sl0][t], wi1, bs1);
        float h1_1 = a1 + fmaf(xls[sl1][t], wi1, bs1);
        __syncthreads();                                   // (1) done reading umask1 old
        upd(mem1[0], sp1[0], h1_0, mbit);
        upd(mem1[1], sp1[1], h1_1, mbit);
        {
            u64 bl0 = __ballot(sp1[0] != 0.0f);
            u64 bl1 = __ballot(sp1[1] != 0.0f);
            if (lane == 0) { umask1[sl0][jg] = bl0; umask1[sl1][jg] = bl1; }
        }
        __syncthreads();                                   // (2) umask1 new visible

        // ---- layer 2: h2 = spk1_new@W2a.T + spk2_old@W2b.T + biases
        float c0, c1, d0, d1;
        matvec_sp(wt2a, j, umask1[sl0], umask1[sl1], c0, c1);
        matvec_sp(wt2b, j, umask2[sl0], umask2[sl1], d0, d1);
        float h2_0 = c0 + d0 + bs2;
        float h2_1 = c1 + d1 + bs2;
        __syncthreads();                                   // (3) done reading umask2 old
        upd(mem2[0], sp2[0], h2_0, mbit);
        upd(mem2[1], sp2[1], h2_1, mbit);
        {
            u64 bl0 = __ballot(sp2[0] != 0.0f);
            u64 bl1 = __ballot(sp2[1] != 0.0f);
            if (lane == 0) { umask2[sl0][jg] = bl0; umask2[sl1][jg] = bl1; }
        }
        __syncthreads();                                   // (4) umask2 new visible

        // ---- layer 3: h3 = spk2_new@W3.T + b
        float e0, e1;
        matvec_sp(wt3, j, umask2[sl0], umask2[sl1], e0, e1);
        upd(mem3[0], sp3[0], e0 + bs3, mbit);
        upd(mem3[1], sp3[1], e1 + bs3, mbit);

        #pragma unroll
        for (int i = 0; i < 10; i++) {
            oacc[0][i] = fmaf(sp3[0], wo[i], oacc[0][i]);
            oacc[1][i] = fmaf(sp3[1], wo[i], oacc[1][i]);
        }

        ph++; if (ph == mc) ph = 0;
    }

    // ---- final reduction: out[s][i] = sum_j oacc
    #pragma unroll
    for (int sl = 0; sl < 2; sl++) {
        #pragma unroll
        for (int i = 0; i < 10; i++) {
            float v = oacc[sl][i];
            for (int off = 32; off; off >>= 1) v += __shfl_down(v, off, 64);
            if (lane == 0) wred[wave][sl][i] = v;
        }
    }
    __syncthreads();
    if (tid < S_PER_BLK * 10) {
        int s = tid / 10, i = tid % 10;
        int sgq = s >> 1, sl = s & 1;
        float sum = 0.f;
        for (int w = 0; w < 4; w++) sum += wred[sgq * 4 + w][sl][i];
        out[(size_t)(s_base + s) * 10 + i] = sum / 784.0f + b_h2o3[i];
    }
}

extern "C" void kernel_launch(void* const* d_in, const int* in_sizes, int n_in,
                              void* d_out, int out_size, void* d_ws, size_t ws_size,
                              hipStream_t stream) {
    (void)in_sizes; (void)n_in; (void)ws_size; (void)out_size;
    const float* x      = (const float*)d_in[0];
    const float* w_i2h1 = (const float*)d_in[1];
    const float* b_i2h1 = (const float*)d_in[2];
    const float* w_h2h1 = (const float*)d_in[3];
    const float* b_h2h1 = (const float*)d_in[4];
    const float* w_i2h2 = (const float*)d_in[5];
    const float* b_i2h2 = (const float*)d_in[6];
    const float* w_h2h2 = (const float*)d_in[7];
    const float* b_h2h2 = (const float*)d_in[8];
    const float* w_i2h3 = (const float*)d_in[9];
    const float* b_i2h3 = (const float*)d_in[10];
    const float* w_h2o3 = (const float*)d_in[11];
    const float* b_h2o3 = (const float*)d_in[12];
    float* ws = (float*)d_ws;   // needs 4*256KB = 1MB

    prep_transpose<<<64, 256, 0, stream>>>(w_h2h1, w_i2h2, w_h2h2, w_i2h3, ws);
    srnn_kernel<<<NBLK, NTHR, 0, stream>>>(x,
        w_i2h1, b_i2h1, b_h2h1,
        b_i2h2, b_h2h2, b_i2h3,
        w_h2o3, b_h2o3, ws,
        (float*)d_out);
}

// Round 3
// 4759.280 us; speedup vs baseline: 9.2595x; 1.9329x over previous
//
#include <hip/hip_runtime.h>
#include <stdint.h>

#define T_STEPS 784
#define H 256
#define NBLK 256        // 512 samples / 2 per block
#define NTHR 512        // 8 waves = 4 jg x 2 kh

typedef unsigned long long u64;

// Per-neuron mask parameters, replicating numpy linspace/ceil/round in float64.
__device__ __forceinline__ void mask_params(int j, int& c, int& on, int& ps) {
    const double stepc = (8.0 - 4.0) / 255.0;
    const double stepd = (0.9 - 0.1) / 255.0;
    const double stepp = 4.0 / 255.0;
    double cyc = (j == 255) ? 8.0 : __dadd_rn(__dmul_rn((double)j, stepc), 4.0);
    c = (int)ceil(cyc);
    double dc  = (j == 255) ? 0.9 : __dadd_rn(__dmul_rn((double)j, stepd), 0.1);
    on = (int)ceil(__dmul_rn(dc, (double)c));
    double psd = (j == 255) ? 4.0 : __dmul_rn((double)j, stepp);
    ps = (int)rint(psd);
}

__device__ __forceinline__ u64 rfl64(u64 v) {
    unsigned int lo = __builtin_amdgcn_readfirstlane((unsigned int)v);
    unsigned int hi = __builtin_amdgcn_readfirstlane((unsigned int)(v >> 32));
    return ((u64)hi << 32) | lo;
}

#define SEL(m,k) ((((m) >> (k)) & 1ull) ? 1.0f : 0.0f)

__device__ __forceinline__ void consume(u64 m0, u64 m1, int k, float w,
                                        float& x0, float& x1) {
    x0 = fmaf(SEL(m0, k), w, x0);
    x1 = fmaf(SEL(m1, k), w, x1);
}

// Sparse accumulate over one 64-row word of a transposed weight matrix.
// mw: uniform base of this word's rows (row k -> mw[k*256 + jv]).
// m0,m1: wave-uniform spike masks for samples 0/1 (SGPR via rfl64 upstream).
// Batches of 8 grouped loads (8 in flight), SGPR-select fmac consumption,
// 4 accumulator chains (a/b x sample). Binary tail 4/2/1, also grouped.
__device__ __forceinline__ void accum_word(const float* __restrict__ mw, int jv,
                                           u64 m0, u64 m1,
                                           float& a0, float& b0, float& a1, float& b1)
{
    u64 u = m0 | m1;
    int n = __popcll(u);
    while (n >= 8) {
        int k0,k1,k2,k3,k4,k5,k6,k7;
        k0=__builtin_ctzll(u); u&=u-1; k1=__builtin_ctzll(u); u&=u-1;
        k2=__builtin_ctzll(u); u&=u-1; k3=__builtin_ctzll(u); u&=u-1;
        k4=__builtin_ctzll(u); u&=u-1; k5=__builtin_ctzll(u); u&=u-1;
        k6=__builtin_ctzll(u); u&=u-1; k7=__builtin_ctzll(u); u&=u-1;
        float w0=mw[(k0<<8)+jv], w1=mw[(k1<<8)+jv], w2=mw[(k2<<8)+jv], w3=mw[(k3<<8)+jv];
        float w4=mw[(k4<<8)+jv], w5=mw[(k5<<8)+jv], w6=mw[(k6<<8)+jv], w7=mw[(k7<<8)+jv];
        consume(m0,m1,k0,w0,a0,a1); consume(m0,m1,k1,w1,b0,b1);
        consume(m0,m1,k2,w2,a0,a1); consume(m0,m1,k3,w3,b0,b1);
        consume(m0,m1,k4,w4,a0,a1); consume(m0,m1,k5,w5,b0,b1);
        consume(m0,m1,k6,w6,a0,a1); consume(m0,m1,k7,w7,b0,b1);
        n -= 8;
    }
    if (n & 4) {
        int k0,k1,k2,k3;
        k0=__builtin_ctzll(u); u&=u-1; k1=__builtin_ctzll(u); u&=u-1;
        k2=__builtin_ctzll(u); u&=u-1; k3=__builtin_ctzll(u); u&=u-1;
        float w0=mw[(k0<<8)+jv], w1=mw[(k1<<8)+jv], w2=mw[(k2<<8)+jv], w3=mw[(k3<<8)+jv];
        consume(m0,m1,k0,w0,a0,a1); consume(m0,m1,k1,w1,b0,b1);
        consume(m0,m1,k2,w2,a0,a1); consume(m0,m1,k3,w3,b0,b1);
    }
    if (n & 2) {
        int k0,k1;
        k0=__builtin_ctzll(u); u&=u-1; k1=__builtin_ctzll(u); u&=u-1;
        float w0=mw[(k0<<8)+jv], w1=mw[(k1<<8)+jv];
        consume(m0,m1,k0,w0,a0,a1); consume(m0,m1,k1,w1,b0,b1);
    }
    if (n & 1) {
        int k0 = __builtin_ctzll(u);
        float w0 = mw[(k0<<8)+jv];
        consume(m0,m1,k0,w0,a0,a1);
    }
}

__device__ __forceinline__ void upd(float& mem, float& sp, float h, int mbit) {
    float nm = fmaf(mem * 0.5f, (1.0f - sp), h);
    mem = mbit ? nm : mem;
    sp  = (mbit && (mem > 0.5f)) ? 1.0f : 0.0f;
}

// Tiled transpose of the 4 weight matrices into ws: WT[k][j] = W[j][k].
__global__ __launch_bounds__(256)
void prep_transpose(const float* __restrict__ w1, const float* __restrict__ w2a,
                    const float* __restrict__ w2b, const float* __restrict__ w3,
                    float* __restrict__ ws)
{
    __shared__ float tile[64][65];
    const int bid = blockIdx.x;                 // 64 blocks: m(4) x kt(4) x jt(4)
    const int m  = bid >> 4;
    const int kt = (bid >> 2) & 3;
    const int jt = bid & 3;
    const float* src = (m == 0) ? w1 : (m == 1) ? w2a : (m == 2) ? w2b : w3;
    float* dst = ws + (size_t)m * H * H;
    const int tid = threadIdx.x;
    const int c = tid & 63, r4 = tid >> 6;
    #pragma unroll
    for (int rr = 0; rr < 16; rr++) {
        int r = r4 * 16 + rr;
        tile[r][c] = src[(size_t)(jt * 64 + r) * H + kt * 64 + c];
    }
    __syncthreads();
    #pragma unroll
    for (int rr = 0; rr < 16; rr++) {
        int r = r4 * 16 + rr;
        dst[(size_t)(kt * 64 + r) * H + jt * 64 + c] = tile[c][r];
    }
}

__global__ __launch_bounds__(NTHR, 4)
void srnn_kernel(const float* __restrict__ x,
                 const float* __restrict__ w_i2h1, const float* __restrict__ b_i2h1,
                 const float* __restrict__ b_h2h1,
                 const float* __restrict__ b_i2h2, const float* __restrict__ b_h2h2,
                 const float* __restrict__ b_i2h3,
                 const float* __restrict__ w_h2o3, const float* __restrict__ b_h2o3,
                 const float* __restrict__ ws,     // WT1 | WT2a | WT2b | WT3
                 float* __restrict__ out)
{
    const int tid  = threadIdx.x;
    const int lane = tid & 63;
    const int wave = tid >> 6;
    const int jg   = wave >> 1;                 // 0..3: j in [64*jg, 64*jg+64)
    const int kh   = wave & 1;                  // k-half: words {2kh, 2kh+1}
    const int j    = jg * 64 + lane;
    const int s_base = blockIdx.x * 2;

    const float* wt1  = ws;
    const float* wt2a = ws + 1 * H * H;
    const float* wt2b = ws + 2 * H * H;
    const float* wt3  = ws + 3 * H * H;
    // This wave's word-base pointers (word w covers rows w*64.., offset w*64*256 floats)
    const int w0i = 2 * kh, w1i = 2 * kh + 1;
    const float* p1a  = wt1  + (w0i << 14); const float* p1b  = wt1  + (w1i << 14);
    const float* p2aa = wt2a + (w0i << 14); const float* p2ab = wt2a + (w1i << 14);
    const float* p2ba = wt2b + (w0i << 14); const float* p2bb = wt2b + (w1i << 14);
    const float* p3a  = wt3  + (w0i << 14); const float* p3b  = wt3  + (w1i << 14);

    __shared__ float xls[2][T_STEPS];           // 6.3 KB
    __shared__ u64 umask1[2][4];                // [sample][word]
    __shared__ u64 umask2[2][4];
    __shared__ float2 pex[3][2][4][64];         // [buf][kh][jg][lane] partials, 12 KB
    __shared__ float wred[4][2][10];

    for (int i = tid; i < 2 * T_STEPS; i += NTHR) {
        int s = i / T_STEPS, t = i - s * T_STEPS;
        xls[s][t] = x[(size_t)(s_base + s) * T_STEPS + t];
    }
    if (tid < 8)  ((u64*)umask1)[tid] = 0ull;
    else if (tid < 16) ((u64*)umask2)[tid - 8] = 0ull;

    int mc, mon, mps;
    mask_params(j, mc, mon, mps);
    int ph = (mc - (mps % mc)) % mc;

    const float bs1 = b_i2h1[j] + b_h2h1[j];
    const float bs2 = b_i2h2[j] + b_h2h2[j];
    const float bs3 = b_i2h3[j];
    const float wi1 = w_i2h1[j];
    float wo[10];
    #pragma unroll
    for (int i = 0; i < 10; i++) wo[i] = w_h2o3[i * H + j];

    // Neuron state for this (j, samples 0/1) — replicated in both kh waves
    // (identical arithmetic -> bitwise-identical state).
    float mem1_0=0.f, mem1_1=0.f, mem2_0=0.f, mem2_1=0.f, mem3_0=0.f, mem3_1=0.f;
    float sp1_0=0.f, sp1_1=0.f, sp2_0=0.f, sp2_1=0.f, sp3_0=0.f, sp3_1=0.f;
    float oacc[2][10];
    #pragma unroll
    for (int i = 0; i < 10; i++) { oacc[0][i] = 0.f; oacc[1][i] = 0.f; }

    __syncthreads();

    for (int t = 0; t < T_STEPS; t++) {
        const int mbit = (ph < mon) ? 1 : 0;

        // ======== layer 1: h1 = x*wi1 + spk1_old@W1.T + biases ========
        {
            u64 m0a = rfl64(umask1[0][w0i]), m1a = rfl64(umask1[1][w0i]);
            u64 m0b = rfl64(umask1[0][w1i]), m1b = rfl64(umask1[1][w1i]);
            float a0=0.f,b0=0.f,a1=0.f,b1=0.f;
            accum_word(p1a, j, m0a, m1a, a0, b0, a1, b1);
            accum_word(p1b, j, m0b, m1b, a0, b0, a1, b1);
            float q0 = a0 + b0, q1 = a1 + b1;
            pex[0][kh][jg][lane] = make_float2(q0, q1);
            __syncthreads();                                     // bar1
            float2 pr = pex[0][kh ^ 1][jg][lane];
            float h1_0 = q0 + pr.x + fmaf(xls[0][t], wi1, bs1);
            float h1_1 = q1 + pr.y + fmaf(xls[1][t], wi1, bs1);
            upd(mem1_0, sp1_0, h1_0, mbit);
            upd(mem1_1, sp1_1, h1_1, mbit);
            u64 bl0 = __ballot(sp1_0 != 0.0f);
            u64 bl1 = __ballot(sp1_1 != 0.0f);
            if (kh == 0 && lane == 0) { umask1[0][jg] = bl0; umask1[1][jg] = bl1; }
        }
        __syncthreads();                                         // bar2

        // ======== layer 2: h2 = spk1_new@W2a.T + spk2_old@W2b.T + biases ========
        {
            u64 n0a = rfl64(umask1[0][w0i]), n1a = rfl64(umask1[1][w0i]);
            u64 n0b = rfl64(umask1[0][w1i]), n1b = rfl64(umask1[1][w1i]);
            u64 o0a = rfl64(umask2[0][w0i]), o1a = rfl64(umask2[1][w0i]);
            u64 o0b = rfl64(umask2[0][w1i]), o1b = rfl64(umask2[1][w1i]);
            float a0=0.f,b0=0.f,a1=0.f,b1=0.f;
            accum_word(p2aa, j, n0a, n1a, a0, b0, a1, b1);
            accum_word(p2ab, j, n0b, n1b, a0, b0, a1, b1);
            accum_word(p2ba, j, o0a, o1a, a0, b0, a1, b1);
            accum_word(p2bb, j, o0b, o1b, a0, b0, a1, b1);
            float q0 = a0 + b0, q1 = a1 + b1;
            pex[1][kh][jg][lane] = make_float2(q0, q1);
            __syncthreads();                                     // bar3
            float2 pr = pex[1][kh ^ 1][jg][lane];
            float h2_0 = q0 + pr.x + bs2;
            float h2_1 = q1 + pr.y + bs2;
            upd(mem2_0, sp2_0, h2_0, mbit);
            upd(mem2_1, sp2_1, h2_1, mbit);
            u64 bl0 = __ballot(sp2_0 != 0.0f);
            u64 bl1 = __ballot(sp2_1 != 0.0f);
            if (kh == 0 && lane == 0) { umask2[0][jg] = bl0; umask2[1][jg] = bl1; }
        }
        __syncthreads();                                         // bar4

        // ======== layer 3: h3 = spk2_new@W3.T + b ========
        {
            u64 m0a = rfl64(umask2[0][w0i]), m1a = rfl64(umask2[1][w0i]);
            u64 m0b = rfl64(umask2[0][w1i]), m1b = rfl64(umask2[1][w1i]);
            float a0=0.f,b0=0.f,a1=0.f,b1=0.f;
            accum_word(p3a, j, m0a, m1a, a0, b0, a1, b1);
            accum_word(p3b, j, m0b, m1b, a0, b0, a1, b1);
            float q0 = a0 + b0, q1 = a1 + b1;
            pex[2][kh][jg][lane] = make_float2(q0, q1);
            __syncthreads();                                     // bar5
            float2 pr = pex[2][kh ^ 1][jg][lane];
            upd(mem3_0, sp3_0, q0 + pr.x + bs3, mbit);
            upd(mem3_1, sp3_1, q1 + pr.y + bs3, mbit);
            #pragma unroll
            for (int i = 0; i < 10; i++) {
                oacc[0][i] = fmaf(sp3_0, wo[i], oacc[0][i]);
                oacc[1][i] = fmaf(sp3_1, wo[i], oacc[1][i]);
            }
        }
        // No barrier needed here: next L1 writes pex[0] (last read before bar2),
        // and reads umask1 written before bar2 — both separated by >=2 barriers.

        ph++; if (ph == mc) ph = 0;
    }

    // ---- final reduction over j: only kh==0 waves contribute (state replicated)
    if (kh == 0) {
        #pragma unroll
        for (int sl = 0; sl < 2; sl++) {
            #pragma unroll
            for (int i = 0; i < 10; i++) {
                float v = oacc[sl][i];
                for (int off = 32; off; off >>= 1) v += __shfl_down(v, off, 64);
                if (lane == 0) wred[jg][sl][i] = v;
            }
        }
    }
    __syncthreads();
    if (tid < 20) {
        int s = tid / 10, i = tid % 10;
        float sum = wred[0][s][i] + wred[1][s][i] + wred[2][s][i] + wred[3][s][i];
        out[(size_t)(s_base + s) * 10 + i] = sum / 784.0f + b_h2o3[i];
    }
}

extern "C" void kernel_launch(void* const* d_in, const int* in_sizes, int n_in,
                              void* d_out, int out_size, void* d_ws, size_t ws_size,
                              hipStream_t stream) {
    (void)in_sizes; (void)n_in; (void)ws_size; (void)out_size;
    const float* x      = (const float*)d_in[0];
    const float* w_i2h1 = (const float*)d_in[1];
    const float* b_i2h1 = (const float*)d_in[2];
    const float* w_h2h1 = (const float*)d_in[3];
    const float* b_h2h1 = (const float*)d_in[4];
    const float* w_i2h2 = (const float*)d_in[5];
    const float* b_i2h2 = (const float*)d_in[6];
    const float* w_h2h2 = (const float*)d_in[7];
    const float* b_h2h2 = (const float*)d_in[8];
    const float* w_i2h3 = (const float*)d_in[9];
    const float* b_i2h3 = (const float*)d_in[10];
    const float* w_h2o3 = (const float*)d_in[11];
    const float* b_h2o3 = (const float*)d_in[12];
    float* ws = (float*)d_ws;   // 4 * 256 KB = 1 MB

    prep_transpose<<<64, 256, 0, stream>>>(w_h2h1, w_i2h2, w_h2h2, w_i2h3, ws);
    srnn_kernel<<<NBLK, NTHR, 0, stream>>>(x,
        w_i2h1, b_i2h1, b_h2h1,
        b_i2h2, b_h2h2, b_i2h3,
        w_h2o3, b_h2o3, ws,
        (float*)d_out);
}

// Round 5
// 2783.497 us; speedup vs baseline: 15.8320x; 1.7098x over previous
//
#include <hip/hip_runtime.h>
#include <stdint.h>

#define T_STEPS 784
#define H 256
#define NBLK 256        // 512 samples / 2 per block
#define NTHR 512        // 8 waves; wave w: consume rows [32w,32w+32), upd (s=w>>2, jg=w&3)

typedef unsigned long long u64;
typedef unsigned int u32;

// Per-neuron mask parameters, replicating numpy linspace/ceil/round in float64.
__device__ __forceinline__ void mask_params(int j, int& c, int& on, int& ps) {
    const double stepc = (8.0 - 4.0) / 255.0;
    const double stepd = (0.9 - 0.1) / 255.0;
    const double stepp = 4.0 / 255.0;
    double cyc = (j == 255) ? 8.0 : __dadd_rn(__dmul_rn((double)j, stepc), 4.0);
    c = (int)ceil(cyc);
    double dc  = (j == 255) ? 0.9 : __dadd_rn(__dmul_rn((double)j, stepd), 0.1);
    on = (int)ceil(__dmul_rn(dc, (double)c));
    double psd = (j == 255) ? 4.0 : __dmul_rn((double)j, stepp);
    ps = (int)rint(psd);
}

__device__ __forceinline__ u32 rfl32(u32 v) {
    return __builtin_amdgcn_readfirstlane(v);
}

// MODE 0: row active for both samples; 1: sample0 only; 2: sample1 only.
template<int MODE>
__device__ __forceinline__ void acc4(const float4& w, float2 acc[4]) {
    if (MODE == 0) {
        acc[0].x += w.x; acc[0].y += w.x;
        acc[1].x += w.y; acc[1].y += w.y;
        acc[2].x += w.z; acc[2].y += w.z;
        acc[3].x += w.w; acc[3].y += w.w;
    } else if (MODE == 1) {
        acc[0].x += w.x; acc[1].x += w.y; acc[2].x += w.z; acc[3].x += w.w;
    } else {
        acc[0].y += w.x; acc[1].y += w.y; acc[2].y += w.z; acc[3].y += w.w;
    }
}

// Sparse accumulate over this wave's 32 rows. m: wave-uniform u32 row mask (SGPR).
// base: matrix base + (w*32 rows)<<10 bytes. Row k -> 1KB apart; lane covers 4 cols.
// 8-deep load batching; VGPR addressing (v_lshl_add of scalar k with lane*16).
template<int MODE>
__device__ __forceinline__ void consume_word(const char* __restrict__ base, u32 m,
                                             int l16, float2 acc[4]) {
    int n = __popc(m);
    while (n >= 8) {
        int k0=__builtin_ctz(m); m&=m-1; int k1=__builtin_ctz(m); m&=m-1;
        int k2=__builtin_ctz(m); m&=m-1; int k3=__builtin_ctz(m); m&=m-1;
        int k4=__builtin_ctz(m); m&=m-1; int k5=__builtin_ctz(m); m&=m-1;
        int k6=__builtin_ctz(m); m&=m-1; int k7=__builtin_ctz(m); m&=m-1;
        float4 w0 = *(const float4*)(base + (k0<<10) + l16);
        float4 w1 = *(const float4*)(base + (k1<<10) + l16);
        float4 w2 = *(const float4*)(base + (k2<<10) + l16);
        float4 w3 = *(const float4*)(base + (k3<<10) + l16);
        float4 w4 = *(const float4*)(base + (k4<<10) + l16);
        float4 w5 = *(const float4*)(base + (k5<<10) + l16);
        float4 w6 = *(const float4*)(base + (k6<<10) + l16);
        float4 w7 = *(const float4*)(base + (k7<<10) + l16);
        acc4<MODE>(w0, acc); acc4<MODE>(w1, acc); acc4<MODE>(w2, acc); acc4<MODE>(w3, acc);
        acc4<MODE>(w4, acc); acc4<MODE>(w5, acc); acc4<MODE>(w6, acc); acc4<MODE>(w7, acc);
        n -= 8;
    }
    if (n & 4) {
        int k0=__builtin_ctz(m); m&=m-1; int k1=__builtin_ctz(m); m&=m-1;
        int k2=__builtin_ctz(m); m&=m-1; int k3=__builtin_ctz(m); m&=m-1;
        float4 w0 = *(const float4*)(base + (k0<<10) + l16);
        float4 w1 = *(const float4*)(base + (k1<<10) + l16);
        float4 w2 = *(const float4*)(base + (k2<<10) + l16);
        float4 w3 = *(const float4*)(base + (k3<<10) + l16);
        acc4<MODE>(w0, acc); acc4<MODE>(w1, acc); acc4<MODE>(w2, acc); acc4<MODE>(w3, acc);
    }
    if (n & 2) {
        int k0=__builtin_ctz(m); m&=m-1; int k1=__builtin_ctz(m); m&=m-1;
        float4 w0 = *(const float4*)(base + (k0<<10) + l16);
        float4 w1 = *(const float4*)(base + (k1<<10) + l16);
        acc4<MODE>(w0, acc); acc4<MODE>(w1, acc);
    }
    if (n & 1) {
        int k0 = __builtin_ctz(m);
        float4 w0 = *(const float4*)(base + (k0<<10) + l16);
        acc4<MODE>(w0, acc);
    }
}

__device__ __forceinline__ void upd(float& mem, float& sp, float h, int mbit) {
    float nm = fmaf(mem * 0.5f, (1.0f - sp), h);
    mem = mbit ? nm : mem;
    sp  = (mbit && (mem > 0.5f)) ? 1.0f : 0.0f;
}

// Tiled transpose of the 4 weight matrices into ws: WT[k][j] = W[j][k].
__global__ __launch_bounds__(256)
void prep_transpose(const float* __restrict__ w1, const float* __restrict__ w2a,
                    const float* __restrict__ w2b, const float* __restrict__ w3,
                    float* __restrict__ ws)
{
    __shared__ float tile[64][65];
    const int bid = blockIdx.x;                 // 64 blocks: m(4) x kt(4) x jt(4)
    const int m  = bid >> 4;
    const int kt = (bid >> 2) & 3;
    const int jt = bid & 3;
    const float* src = (m == 0) ? w1 : (m == 1) ? w2a : (m == 2) ? w2b : w3;
    float* dst = ws + (size_t)m * H * H;
    const int tid = threadIdx.x;
    const int c = tid & 63, r4 = tid >> 6;
    #pragma unroll
    for (int rr = 0; rr < 16; rr++) {
        int r = r4 * 16 + rr;
        tile[r][c] = src[(size_t)(jt * 64 + r) * H + kt * 64 + c];
    }
    __syncthreads();
    #pragma unroll
    for (int rr = 0; rr < 16; rr++) {
        int r = r4 * 16 + rr;
        dst[(size_t)(kt * 64 + r) * H + jt * 64 + c] = tile[c][r];
    }
}

__global__ __launch_bounds__(NTHR, 2)
void srnn_kernel(const float* __restrict__ x,
                 const float* __restrict__ w_i2h1, const float* __restrict__ b_i2h1,
                 const float* __restrict__ b_h2h1,
                 const float* __restrict__ b_i2h2, const float* __restrict__ b_h2h2,
                 const float* __restrict__ b_i2h3,
                 const float* __restrict__ w_h2o3, const float* __restrict__ b_h2o3,
                 const float* __restrict__ ws,     // WT1 | WT2a | WT2b | WT3
                 float* __restrict__ out)
{
    const int tid  = threadIdx.x;
    const int lane = tid & 63;
    const int w    = tid >> 6;         // wave id
    const int s_up = w >> 2;           // upd role: sample
    const int jg   = w & 3;            // upd role: j-range
    const int j    = jg * 64 + lane;   // upd neuron
    const int l16  = lane * 16;        // consume role: byte offset into each row
    const int s_base = blockIdx.x * 2;

    const char* wt1  = (const char*)ws + (w << 15);                // rows [32w,32w+32)
    const char* wt2a = (const char*)ws + (1 << 18) + (w << 15);
    const char* wt2b = (const char*)ws + (2 << 18) + (w << 15);
    const char* wt3  = (const char*)ws + (3 << 18) + (w << 15);

    __shared__ float xls[2][T_STEPS];       // 6.3 KB
    __shared__ u64 um1[2][4];               // [s][word64]
    __shared__ u64 um2[2][4];
    __shared__ float pexA[8 * 576];         // [wave][lane][9]: partials, 18.4 KB
    __shared__ float pexB[8 * 576];
    __shared__ float wred[8][10];

    for (int i = tid; i < 2 * T_STEPS; i += NTHR) {
        int s = i / T_STEPS, t = i - s * T_STEPS;
        xls[s][t] = x[(size_t)(s_base + s) * T_STEPS + t];
    }
    if (tid < 8) ((u64*)um1)[tid] = 0ull;
    else if (tid < 16) ((u64*)um2)[tid - 8] = 0ull;

    int mc, mon, mps;
    mask_params(j, mc, mon, mps);
    int ph = (mc - (mps % mc)) % mc;

    const float bs1 = b_i2h1[j] + b_h2h1[j];
    const float bs2 = b_i2h2[j] + b_h2h2[j];
    const float bs3 = b_i2h3[j];
    const float wi1 = w_i2h1[j];
    float wo[10];
    #pragma unroll
    for (int i = 0; i < 10; i++) wo[i] = w_h2o3[i * H + j];

    float mem1 = 0.f, mem2 = 0.f, mem3 = 0.f;
    float sp1 = 0.f, sp2 = 0.f, sp3 = 0.f;
    float oacc[10];
    #pragma unroll
    for (int i = 0; i < 10; i++) oacc[i] = 0.f;

    const int pwb = w * 576 + lane * 9;                      // consume write base (dwords)
    const int prb = (j >> 2) * 9 + (j & 3) * 2 + s_up;       // upd read offset in a wave-seg
    const u32* um1v = (const u32*)um1;                       // [s*8 + word64*2 + half]
    const u32* um2v = (const u32*)um2;
    const int mi = (w >> 1) * 2 + (w & 1);                   // this wave's u32 index (per s)

    __syncthreads();

    for (int t = 0; t < T_STEPS; t++) {
        const int mbit = (ph < mon) ? 1 : 0;

        // ---- a: consume L1 = spk1_old @ W1^T  -> pexA
        {
            u32 m0 = rfl32(um1v[mi]), m1 = rfl32(um1v[8 + mi]);
            float2 acc[4] = {{0.f,0.f},{0.f,0.f},{0.f,0.f},{0.f,0.f}};
            consume_word<0>(wt1, m0 & m1,  l16, acc);
            consume_word<1>(wt1, m0 & ~m1, l16, acc);
            consume_word<2>(wt1, m1 & ~m0, l16, acc);
            #pragma unroll
            for (int q = 0; q < 4; q++) {
                pexA[pwb + 2*q]     = acc[q].x;
                pexA[pwb + 2*q + 1] = acc[q].y;
            }
        }
        __syncthreads();                                     // B1

        // ---- b: upd1, publish spike mask 1
        {
            float hs = 0.f;
            #pragma unroll
            for (int q = 0; q < 8; q++) hs += pexA[q * 576 + prb];
            float h1 = hs + fmaf(xls[s_up][t], wi1, bs1);
            upd(mem1, sp1, h1, mbit);
            u64 bl = __ballot(sp1 != 0.0f);
            if (lane == 0) um1[s_up][jg] = bl;
        }
        __syncthreads();                                     // B2

        // ---- c: consume L2 = spk1_new @ W2a^T + spk2_old @ W2b^T -> pexB
        {
            u32 n0 = rfl32(um1v[mi]), n1 = rfl32(um1v[8 + mi]);
            u32 o0 = rfl32(um2v[mi]), o1 = rfl32(um2v[8 + mi]);
            float2 acc[4] = {{0.f,0.f},{0.f,0.f},{0.f,0.f},{0.f,0.f}};
            consume_word<0>(wt2a, n0 & n1,  l16, acc);
            consume_word<1>(wt2a, n0 & ~n1, l16, acc);
            consume_word<2>(wt2a, n1 & ~n0, l16, acc);
            consume_word<0>(wt2b, o0 & o1,  l16, acc);
            consume_word<1>(wt2b, o0 & ~o1, l16, acc);
            consume_word<2>(wt2b, o1 & ~o0, l16, acc);
            #pragma unroll
            for (int q = 0; q < 4; q++) {
                pexB[pwb + 2*q]     = acc[q].x;
                pexB[pwb + 2*q + 1] = acc[q].y;
            }
        }
        __syncthreads();                                     // B3

        // ---- d: upd2, publish spike mask 2
        {
            float hs = 0.f;
            #pragma unroll
            for (int q = 0; q < 8; q++) hs += pexB[q * 576 + prb];
            upd(mem2, sp2, hs + bs2, mbit);
            u64 bl = __ballot(sp2 != 0.0f);
            if (lane == 0) um2[s_up][jg] = bl;
        }
        __syncthreads();                                     // B4

        // ---- e: consume L3 = spk2_new @ W3^T -> pexA
        {
            u32 m0 = rfl32(um2v[mi]), m1 = rfl32(um2v[8 + mi]);
            float2 acc[4] = {{0.f,0.f},{0.f,0.f},{0.f,0.f},{0.f,0.f}};
            consume_word<0>(wt3, m0 & m1,  l16, acc);
            consume_word<1>(wt3, m0 & ~m1, l16, acc);
            consume_word<2>(wt3, m1 & ~m0, l16, acc);
            #pragma unroll
            for (int q = 0; q < 4; q++) {
                pexA[pwb + 2*q]     = acc[q].x;
                pexA[pwb + 2*q + 1] = acc[q].y;
            }
        }
        __syncthreads();                                     // B5

        // ---- f: upd3, output accumulation
        {
            float hs = 0.f;
            #pragma unroll
            for (int q = 0; q < 8; q++) hs += pexA[q * 576 + prb];
            upd(mem3, sp3, hs + bs3, mbit);
            #pragma unroll
            for (int i = 0; i < 10; i++) oacc[i] = fmaf(sp3, wo[i], oacc[i]);
        }
        __syncthreads();                                     // B6 (pexA reused by next a)

        ph++; if (ph == mc) ph = 0;
    }

    // ---- final reduction over j within each upd-wave
    #pragma unroll
    for (int i = 0; i < 10; i++) {
        float v = oacc[i];
        for (int off = 32; off; off >>= 1) v += __shfl_down(v, off, 64);
        if (lane == 0) wred[w][i] = v;
    }
    __syncthreads();
    if (tid < 20) {
        int s = tid / 10, i = tid % 10;
        float sum = wred[s*4 + 0][i] + wred[s*4 + 1][i] + wred[s*4 + 2][i] + wred[s*4 + 3][i];
        out[(size_t)(s_base + s) * 10 + i] = sum / 784.0f + b_h2o3[i];
    }
}

extern "C" void kernel_launch(void* const* d_in, const int* in_sizes, int n_in,
                              void* d_out, int out_size, void* d_ws, size_t ws_size,
                              hipStream_t stream) {
    (void)in_sizes; (void)n_in; (void)ws_size; (void)out_size;
    const float* x      = (const float*)d_in[0];
    const float* w_i2h1 = (const float*)d_in[1];
    const float* b_i2h1 = (const float*)d_in[2];
    const float* w_h2h1 = (const float*)d_in[3];
    const float* b_h2h1 = (const float*)d_in[4];
    const float* w_i2h2 = (const float*)d_in[5];
    const float* b_i2h2 = (const float*)d_in[6];
    const float* w_h2h2 = (const float*)d_in[7];
    const float* b_h2h2 = (const float*)d_in[8];
    const float* w_i2h3 = (const float*)d_in[9];
    const float* b_i2h3 = (const float*)d_in[10];
    const float* w_h2o3 = (const float*)d_in[11];
    const float* b_h2o3 = (const float*)d_in[12];
    float* ws = (float*)d_ws;   // 4 * 256 KB = 1 MB

    prep_transpose<<<64, 256, 0, stream>>>(w_h2h1, w_i2h2, w_h2h2, w_i2h3, ws);
    srnn_kernel<<<NBLK, NTHR, 0, stream>>>(x,
        w_i2h1, b_i2h1, b_h2h1,
        b_i2h2, b_h2h2, b_i2h3,
        w_h2o3, b_h2o3, ws,
        (float*)d_out);
}

// Round 6
// 2201.953 us; speedup vs baseline: 20.0133x; 1.2641x over previous
//
#include <hip/hip_runtime.h>
#include <stdint.h>

#define T_STEPS 784
#define H 256
#define NBLK 512        // 1 sample per block
#define NTHR 256        // 4 waves; wave w owns neurons AND rows [64w, 64w+64)

typedef unsigned long long u64;

// Per-neuron mask parameters, replicating numpy linspace/ceil/round in float64.
__device__ __forceinline__ void mask_params(int j, int& c, int& on, int& ps) {
    const double stepc = (8.0 - 4.0) / 255.0;
    const double stepd = (0.9 - 0.1) / 255.0;
    const double stepp = 4.0 / 255.0;
    double cyc = (j == 255) ? 8.0 : __dadd_rn(__dmul_rn((double)j, stepc), 4.0);
    c = (int)ceil(cyc);
    double dc  = (j == 255) ? 0.9 : __dadd_rn(__dmul_rn((double)j, stepd), 0.1);
    on = (int)ceil(__dmul_rn(dc, (double)c));
    double psd = (j == 255) ? 4.0 : __dmul_rn((double)j, stepp);
    ps = (int)rint(psd);
}

__device__ __forceinline__ void acc_add(const float4& w, float4& a) {
    a.x += w.x; a.y += w.y; a.z += w.z; a.w += w.w;
}

// Sparse accumulate over this wave's 64 rows. m: wave's own spike ballot (SGPR,
// loop-carried in registers — never goes through LDS). base: matrix base for
// rows [64w..64w+64) (row k local -> 1KB apart); lane covers 4 cols via l16.
// 8-deep load batching for MLP; binary tail.
__device__ __forceinline__ void consume64(const char* __restrict__ base, u64 m,
                                          int l16, float4& acc) {
    int n = __popcll(m);
    while (n >= 8) {
        int k0=__builtin_ctzll(m); m&=m-1; int k1=__builtin_ctzll(m); m&=m-1;
        int k2=__builtin_ctzll(m); m&=m-1; int k3=__builtin_ctzll(m); m&=m-1;
        int k4=__builtin_ctzll(m); m&=m-1; int k5=__builtin_ctzll(m); m&=m-1;
        int k6=__builtin_ctzll(m); m&=m-1; int k7=__builtin_ctzll(m); m&=m-1;
        float4 w0 = *(const float4*)(base + (k0<<10) + l16);
        float4 w1 = *(const float4*)(base + (k1<<10) + l16);
        float4 w2 = *(const float4*)(base + (k2<<10) + l16);
        float4 w3 = *(const float4*)(base + (k3<<10) + l16);
        float4 w4 = *(const float4*)(base + (k4<<10) + l16);
        float4 w5 = *(const float4*)(base + (k5<<10) + l16);
        float4 w6 = *(const float4*)(base + (k6<<10) + l16);
        float4 w7 = *(const float4*)(base + (k7<<10) + l16);
        acc_add(w0, acc); acc_add(w1, acc); acc_add(w2, acc); acc_add(w3, acc);
        acc_add(w4, acc); acc_add(w5, acc); acc_add(w6, acc); acc_add(w7, acc);
        n -= 8;
    }
    if (n & 4) {
        int k0=__builtin_ctzll(m); m&=m-1; int k1=__builtin_ctzll(m); m&=m-1;
        int k2=__builtin_ctzll(m); m&=m-1; int k3=__builtin_ctzll(m); m&=m-1;
        float4 w0 = *(const float4*)(base + (k0<<10) + l16);
        float4 w1 = *(const float4*)(base + (k1<<10) + l16);
        float4 w2 = *(const float4*)(base + (k2<<10) + l16);
        float4 w3 = *(const float4*)(base + (k3<<10) + l16);
        acc_add(w0, acc); acc_add(w1, acc); acc_add(w2, acc); acc_add(w3, acc);
    }
    if (n & 2) {
        int k0=__builtin_ctzll(m); m&=m-1; int k1=__builtin_ctzll(m); m&=m-1;
        float4 w0 = *(const float4*)(base + (k0<<10) + l16);
        float4 w1 = *(const float4*)(base + (k1<<10) + l16);
        acc_add(w0, acc); acc_add(w1, acc);
    }
    if (n & 1) {
        int k0 = __builtin_ctzll(m);
        float4 w0 = *(const float4*)(base + (k0<<10) + l16);
        acc_add(w0, acc);
    }
}

__device__ __forceinline__ void upd(float& mem, float& sp, float h, int mbit) {
    float nm = fmaf(mem * 0.5f, (1.0f - sp), h);
    mem = mbit ? nm : mem;
    sp  = (mbit && (mem > 0.5f)) ? 1.0f : 0.0f;
}

// Tiled transpose of the 4 weight matrices into ws: WT[k][j] = W[j][k].
__global__ __launch_bounds__(256)
void prep_transpose(const float* __restrict__ w1, const float* __restrict__ w2a,
                    const float* __restrict__ w2b, const float* __restrict__ w3,
                    float* __restrict__ ws)
{
    __shared__ float tile[64][65];
    const int bid = blockIdx.x;                 // 64 blocks: m(4) x kt(4) x jt(4)
    const int m  = bid >> 4;
    const int kt = (bid >> 2) & 3;
    const int jt = bid & 3;
    const float* src = (m == 0) ? w1 : (m == 1) ? w2a : (m == 2) ? w2b : w3;
    float* dst = ws + (size_t)m * H * H;
    const int tid = threadIdx.x;
    const int c = tid & 63, r4 = tid >> 6;
    #pragma unroll
    for (int rr = 0; rr < 16; rr++) {
        int r = r4 * 16 + rr;
        tile[r][c] = src[(size_t)(jt * 64 + r) * H + kt * 64 + c];
    }
    __syncthreads();
    #pragma unroll
    for (int rr = 0; rr < 16; rr++) {
        int r = r4 * 16 + rr;
        dst[(size_t)(kt * 64 + r) * H + jt * 64 + c] = tile[c][r];
    }
}

__global__ __launch_bounds__(NTHR, 2)
void srnn_kernel(const float* __restrict__ x,
                 const float* __restrict__ w_i2h1, const float* __restrict__ b_i2h1,
                 const float* __restrict__ b_h2h1,
                 const float* __restrict__ b_i2h2, const float* __restrict__ b_h2h2,
                 const float* __restrict__ b_i2h3,
                 const float* __restrict__ w_h2o3, const float* __restrict__ b_h2o3,
                 const float* __restrict__ ws,     // WT1 | WT2a | WT2b | WT3
                 float* __restrict__ out)
{
    const int tid  = threadIdx.x;
    const int lane = tid & 63;
    const int w    = tid >> 6;         // wave id = j-group = row-group
    const int j    = w * 64 + lane;    // this thread's neuron
    const int l16  = lane * 16;        // byte offset into each row (4 cols/lane)
    const int s    = blockIdx.x;       // sample

    // Wave's row-slice base per matrix: rows [64w, 64w+64), 64KB per slice.
    const char* wt1  = (const char*)ws + (0 << 18) + (w << 16);
    const char* wt2a = (const char*)ws + (1 << 18) + (w << 16);
    const char* wt2b = (const char*)ws + (2 << 18) + (w << 16);
    const char* wt3  = (const char*)ws + (3 << 18) + (w << 16);

    __shared__ float xls[T_STEPS];          // 3.1 KB
    __shared__ float pexA[4][H];            // per-wave partials, 4 KB each
    __shared__ float pexB[4][H];
    __shared__ float pexC[4][H];
    __shared__ float wred[4][10];

    for (int i = tid; i < T_STEPS; i += NTHR)
        xls[i] = x[(size_t)s * T_STEPS + i];

    int mc, mon, mps;
    mask_params(j, mc, mon, mps);
    int ph = (mc - (mps % mc)) % mc;

    const float bs1 = b_i2h1[j] + b_h2h1[j];
    const float bs2 = b_i2h2[j] + b_h2h2[j];
    const float bs3 = b_i2h3[j];
    const float wi1 = w_i2h1[j];
    float wo[10];
    #pragma unroll
    for (int i = 0; i < 10; i++) wo[i] = w_h2o3[i * H + j];

    float mem1 = 0.f, mem2 = 0.f, mem3 = 0.f;
    float sp1 = 0.f, sp2 = 0.f, sp3 = 0.f;
    u64 bal1 = 0ull, bal2 = 0ull;      // this wave's spike masks, register-resident
    float oacc[10];
    #pragma unroll
    for (int i = 0; i < 10; i++) oacc[i] = 0.f;

    __syncthreads();

    for (int t = 0; t < T_STEPS; t++) {
        const int mbit = (ph < mon) ? 1 : 0;

        // ---- a: L1 partials = spk1_old(rows of this wave) @ W1^T
        {
            float4 a = {0.f, 0.f, 0.f, 0.f};
            consume64(wt1, bal1, l16, a);
            ((float4*)pexA[w])[lane] = a;             // ds_write_b128, conflict-free
        }
        __syncthreads();                              // B1: pexA visible

        // ---- b: upd1 (reads pexA), new ballot stays in registers
        {
            float hs = pexA[0][j] + pexA[1][j] + pexA[2][j] + pexA[3][j];
            float h1 = hs + fmaf(xls[t], wi1, bs1);
            upd(mem1, sp1, h1, mbit);
            bal1 = __ballot(sp1 != 0.0f);
        }
        // ---- c: L2 partials = spk1_new @ W2a^T + spk2_old @ W2b^T
        // (no barrier needed: writes pexB only, reads only own registers)
        {
            float4 a = {0.f, 0.f, 0.f, 0.f};
            consume64(wt2a, bal1, l16, a);
            consume64(wt2b, bal2, l16, a);
            ((float4*)pexB[w])[lane] = a;
        }
        __syncthreads();                              // B2: pexB visible

        // ---- d: upd2
        {
            float hs = pexB[0][j] + pexB[1][j] + pexB[2][j] + pexB[3][j];
            upd(mem2, sp2, hs + bs2, mbit);
            bal2 = __ballot(sp2 != 0.0f);
        }
        // ---- e: L3 partials = spk2_new @ W3^T
        {
            float4 a = {0.f, 0.f, 0.f, 0.f};
            consume64(wt3, bal2, l16, a);
            ((float4*)pexC[w])[lane] = a;
        }
        __syncthreads();                              // B3: pexC visible

        // ---- f: upd3 + output accumulation (next a rewrites pexA: its last
        // read was phase b, ≥2 barriers back for every wave — safe)
        {
            float hs = pexC[0][j] + pexC[1][j] + pexC[2][j] + pexC[3][j];
            upd(mem3, sp3, hs + bs3, mbit);
            #pragma unroll
            for (int i = 0; i < 10; i++) oacc[i] = fmaf(sp3, wo[i], oacc[i]);
        }

        ph++; if (ph == mc) ph = 0;
    }

    // ---- final reduction over lanes, then waves
    #pragma unroll
    for (int i = 0; i < 10; i++) {
        float v = oacc[i];
        for (int off = 32; off; off >>= 1) v += __shfl_down(v, off, 64);
        if (lane == 0) wred[w][i] = v;
    }
    __syncthreads();
    if (tid < 10) {
        float sum = wred[0][tid] + wred[1][tid] + wred[2][tid] + wred[3][tid];
        out[(size_t)s * 10 + tid] = sum / 784.0f + b_h2o3[tid];
    }
}

extern "C" void kernel_launch(void* const* d_in, const int* in_sizes, int n_in,
                              void* d_out, int out_size, void* d_ws, size_t ws_size,
                              hipStream_t stream) {
    (void)in_sizes; (void)n_in; (void)ws_size; (void)out_size;
    const float* x      = (const float*)d_in[0];
    const float* w_i2h1 = (const float*)d_in[1];
    const float* b_i2h1 = (const float*)d_in[2];
    const float* w_h2h1 = (const float*)d_in[3];
    const float* b_h2h1 = (const float*)d_in[4];
    const float* w_i2h2 = (const float*)d_in[5];
    const float* b_i2h2 = (const float*)d_in[6];
    const float* w_h2h2 = (const float*)d_in[7];
    const float* b_h2h2 = (const float*)d_in[8];
    const float* w_i2h3 = (const float*)d_in[9];
    const float* b_i2h3 = (const float*)d_in[10];
    const float* w_h2o3 = (const float*)d_in[11];
    const float* b_h2o3 = (const float*)d_in[12];
    float* ws = (float*)d_ws;   // 4 * 256 KB = 1 MB

    prep_transpose<<<64, 256, 0, stream>>>(w_h2h1, w_i2h2, w_h2h2, w_i2h3, ws);
    srnn_kernel<<<NBLK, NTHR, 0, stream>>>(x,
        w_i2h1, b_i2h1, b_h2h1,
        b_i2h2, b_h2h2, b_i2h3,
        w_h2o3, b_h2o3, ws,
        (float*)d_out);
}